// Round 16
// baseline (284.676 us; speedup 1.0000x reference)
//
#include <hip/hip_runtime.h>

constexpr int Bn = 8, Cn = 3, Hn = 720, Wn = 1280;
constexpr int HW = Hn * Wn;                    // 921600 px per image
constexpr long long NTOT = (long long)Bn * Cn * HW;

constexpr int BLK  = 256;
constexpr int TH   = 16, TW = 64;              // output tile 16x64 = 1024 px
constexpr int TCOL = Wn / TW;                  // 20 tile-cols
constexpr int TPI  = (Hn / TH) * TCOL;         // 900 tiles per image
constexpr int NWG  = 8 * Cn * TPI;             // 21600 blocks: (tile,channel) x image
constexpr int PXT  = (TH * TW) / BLK;          // 4 px per thread
constexpr int WR   = 24;                       // window rows: Y-4 .. Y+19 (border-replicated)
constexpr int WC   = 84;                       // window cols: XS-4 .. XS+79
constexpr int F4W  = WC / 4;                   // 21 f4 per window row
constexpr int F4P  = WR * F4W;                 // 504 f4 per plane
constexpr int NF4  = 2 * F4P;                  // 1008 f4 (both planes, one channel)

typedef float f4 __attribute__((ext_vector_type(4)));

__global__ __launch_bounds__(256) void warp_loss_kernel(
        const float* __restrict__ L, const float* __restrict__ R,
        const float* __restrict__ Flm, const float* __restrict__ Frm,
        const float* __restrict__ G, double* __restrict__ accum) {
    // block = (image=bid&7 -> XCD, channel, tile). The 3 channel-blocks of a
    // tile are grid-adjacent -> co-resident on the same XCD -> flow/L2 reuse.
    // One channel per block => single 16.1KB window, 2 barriers, short блок.
    const int b    = blockIdx.x & 7;
    const int t3   = blockIdx.x >> 3;          // [0, 2700)
    const int c    = t3 % 3;
    const int t    = t3 / 3;                   // [0, 900)
    const int trow = t / TCOL;
    const int tcol = t - trow * TCOL;
    const int Y    = trow * TH;
    const int XS   = tcol * TW;
    const int tid  = (int)threadIdx.x;

    const float* __restrict__ Lc = L + ((size_t)b * Cn + c) * HW;
    const float* __restrict__ Rc = R + ((size_t)b * Cn + c) * HW;
    const float* __restrict__ Gc = G + ((size_t)b * Cn + c) * HW;
    const float* __restrict__ fl = Flm + (size_t)b * 2 * HW;  // [0,HW)=x, [HW,2HW)=y
    const float* __restrict__ fr = Frm + (size_t)b * 2 * HW;

    __shared__ float win[2][WR][WC];           // 16.1 KB: L_c and R_c windows

    // ---- stage both planes' windows: 1008 f4, fully coalesced ----
    #pragma unroll
    for (int k = 0; k < 4; ++k) {
        const int idx = k * BLK + tid;
        if (idx < NF4) {
            const int pl = idx >= F4P;
            const int f  = idx - pl * F4P;
            const int wr = f / F4W;
            const int c4 = f - wr * F4W;
            const int ys = min(max(Y - 4 + wr, 0), Hn - 1);
            const int xw = XS - 4 + c4 * 4;
            const float* __restrict__ src = (pl ? Rc : Lc) + (size_t)ys * Wn;
            f4 v;
            if (xw >= 0 && xw + 3 < Wn) {
                v = *reinterpret_cast<const f4*>(src + xw);   // 16B-aligned
            } else {
                v[0] = src[min(max(xw,     0), Wn - 1)];
                v[1] = src[min(max(xw + 1, 0), Wn - 1)];
                v[2] = src[min(max(xw + 2, 0), Wn - 1)];
                v[3] = src[min(max(xw + 3, 0), Wn - 1)];
            }
            *reinterpret_cast<f4*>(&win[pl][wr][c4 * 4]) = v;
        }
    }
    __syncthreads();

    // ---- per-px: taps + sample (flow loads overlap the staging latency
    //      above only via other waves; per-block path is now short) ----
    float local = 0.f;
    const float* __restrict__ w0 = &win[0][0][0];
    const float* __restrict__ w1 = &win[1][0][0];
    #pragma unroll
    for (int k = 0; k < PXT; ++k) {
        const int i = k * BLK + tid;
        const int r = i >> 6, cm = i & 63;
        const int y = Y + r, x = XS + cm;
        const int p = y * Wn + x;

        const float g = Gc[p];

        {   // L warp
            const float fx = fminf(fmaxf(fl[p],      -4.0f), 3.99951171875f);
            const float fy = fminf(fmaxf(fl[HW + p], -4.0f), 3.99951171875f);
            const float xc = fminf(fmaxf((float)x + fx, 0.f), (float)(Wn - 1));
            const float yc = fminf(fmaxf((float)y + fy, 0.f), (float)(Hn - 1));
            const float x0f = floorf(xc), y0f = floorf(yc);
            const float wx = xc - x0f, wy = yc - y0f;
            const int a = ((int)y0f - (Y - 4)) * WC + ((int)x0f - (XS - 4));
            const float v00 = w0[a],      v01 = w0[a + 1];
            const float v10 = w0[a + WC], v11 = w0[a + WC + 1];
            const float top = fmaf(wx, v01 - v00, v00);
            const float bot = fmaf(wx, v11 - v10, v10);
            local += fabsf(fmaf(wy, bot - top, top) - g);
        }
        {   // R warp
            const float fx = fminf(fmaxf(fr[p],      -4.0f), 3.99951171875f);
            const float fy = fminf(fmaxf(fr[HW + p], -4.0f), 3.99951171875f);
            const float xc = fminf(fmaxf((float)x + fx, 0.f), (float)(Wn - 1));
            const float yc = fminf(fmaxf((float)y + fy, 0.f), (float)(Hn - 1));
            const float x0f = floorf(xc), y0f = floorf(yc);
            const float wx = xc - x0f, wy = yc - y0f;
            const int a = ((int)y0f - (Y - 4)) * WC + ((int)x0f - (XS - 4));
            const float v00 = w1[a],      v01 = w1[a + 1];
            const float v10 = w1[a + WC], v11 = w1[a + WC + 1];
            const float top = fmaf(wx, v01 - v00, v00);
            const float bot = fmaf(wx, v11 - v10, v10);
            local += fabsf(fmaf(wy, bot - top, top) - g);
        }
    }

    // wave(64) shuffle reduce -> LDS cross-wave -> one f64 atomic per block
    #pragma unroll
    for (int off = 32; off > 0; off >>= 1)
        local += __shfl_down(local, off, 64);

    __shared__ float wsum[4];
    const int lane = tid & 63;
    const int wid  = tid >> 6;
    if (lane == 0) wsum[wid] = local;
    __syncthreads();
    if (tid == 0) {
        const float s = wsum[0] + wsum[1] + wsum[2] + wsum[3];
        atomicAdd(accum, (double)s);
    }
}

__global__ void finalize_kernel(const double* __restrict__ accum,
                                float* __restrict__ out) {
    out[0] = (float)(accum[0] / (double)NTOT);
}

extern "C" void kernel_launch(void* const* d_in, const int* in_sizes, int n_in,
                              void* d_out, int out_size, void* d_ws, size_t ws_size,
                              hipStream_t stream) {
    const float* L   = (const float*)d_in[0];
    const float* R   = (const float*)d_in[1];
    const float* flm = (const float*)d_in[2];
    const float* frm = (const float*)d_in[3];
    const float* gt  = (const float*)d_in[4];
    double* accum = (double*)d_ws;

    (void)hipMemsetAsync(accum, 0, sizeof(double), stream);
    warp_loss_kernel<<<NWG, BLK, 0, stream>>>(L, R, flm, frm, gt, accum);
    finalize_kernel<<<1, 1, 0, stream>>>(accum, (float*)d_out);
}

// Round 17
// 123.498 us; speedup vs baseline: 2.3051x; 2.3051x over previous
//
#include <hip/hip_runtime.h>
#include <stdint.h>

constexpr int Bn = 8, Cn = 3, Hn = 720, Wn = 1280;
constexpr int HW = Hn * Wn;                    // 921600 px per image
constexpr long long NTOT = (long long)Bn * Cn * HW;

constexpr int BLK  = 256;
constexpr int TH   = 16, TW = 64;              // output tile 16x64 = 1024 px
constexpr int TCOL = Wn / TW;                  // 20 tile-cols
constexpr int TPI  = (Hn / TH) * TCOL;         // 900 tiles per image
constexpr int NWG  = 8 * TPI;                  // 7200 blocks; bid&7 = image/XCD
constexpr int PXT  = (TH * TW) / BLK;          // 4 px per thread
constexpr int WR   = 24;                       // window rows: Y-4 .. Y+19 (border-replicated)
constexpr int WC   = 84;                       // window cols: XS-4 .. XS+79
constexpr int F4W  = WC / 4;                   // 21 f4 per window row
constexpr int F4P  = WR * F4W;                 // 504 real f4 per plane
constexpr int PSTR = 2048;                     // plane stride in floats (512 f4 = 8KB, padded)
constexpr int BUFF = 2 * PSTR;                 // 4096 floats = 16KB per channel buffer

// async global->LDS DMA, 16B per lane; LDS dest is wave-uniform base + lane*16
#define GLOAD_LDS16(gsrc, ldst) \
    __builtin_amdgcn_global_load_lds( \
        (const __attribute__((address_space(1))) void*)(gsrc), \
        (__attribute__((address_space(3))) void*)(ldst), 16, 0, 0)

__global__ __launch_bounds__(256) void warp_loss_kernel(
        const float* __restrict__ L, const float* __restrict__ R,
        const float* __restrict__ Flm, const float* __restrict__ Frm,
        const float* __restrict__ G, double* __restrict__ accum) {
    // XCD k (= bid%8) owns image k; t = tile id, row-major sweep (halo in L2).
    const int b    = blockIdx.x & 7;
    const int t    = blockIdx.x >> 3;          // [0, 900)
    const int trow = t / TCOL;
    const int tcol = t - trow * TCOL;
    const int Y    = trow * TH;
    const int XS   = tcol * TW;
    const int tid  = (int)threadIdx.x;

    const float* __restrict__ Lb = L + (size_t)b * Cn * HW;
    const float* __restrict__ Rb = R + (size_t)b * Cn * HW;
    const float* __restrict__ Gb = G + (size_t)b * Cn * HW;
    const float* __restrict__ fl = Flm + (size_t)b * 2 * HW;  // [0,HW)=x, [HW,2HW)=y
    const float* __restrict__ fr = Frm + (size_t)b * 2 * HW;

    __shared__ float win[2][BUFF];             // 32 KB: double-buffered L+R windows

    // ---- channel-invariant staging source offsets (slot layout:
    //      k rounds; k>>1 = plane, f = (k&1)*256+tid; pad slots f>=504 clamp) ----
    int soff[2];
    #pragma unroll
    for (int k1 = 0; k1 < 2; ++k1) {
        const int f  = min(k1 * BLK + tid, F4P - 1);
        const int wr = f / F4W;
        const int c4 = f - wr * F4W;
        const int ys = min(max(Y - 4 + wr, 0), Hn - 1);
        const int xw = min(max(XS - 4 + c4 * 4, 0), Wn - 4);  // 16B-aligned, in-bounds
        soff[k1] = ys * Wn + xw;
    }
    const int wave16 = (tid & 192);            // wave-uniform slot base within round

    // ---- prologue: issue channel-0 DMA, then tap preamble overlaps it ----
    {
        const float* __restrict__ Lc = Lb;
        const float* __restrict__ Rc = Rb;
        #pragma unroll
        for (int k = 0; k < 4; ++k) {
            const float* src = ((k >> 1) ? Rc : Lc) + soff[k & 1];
            float* dst = &win[0][(size_t)(k * BLK + wave16) * 4];
            GLOAD_LDS16(src, dst);
        }
    }

    // ---- per-px tap state (channel-invariant), coalesced flow loads ----
    int   aL[PXT], aR[PXT];
    float lwx[PXT], lwy[PXT], rwx[PXT], rwy[PXT];
    #pragma unroll
    for (int k = 0; k < PXT; ++k) {
        const int i = k * BLK + tid;
        const int r = i >> 6, cm = i & 63;
        const int y = Y + r, x = XS + cm;
        const int p = y * Wn + x;
        {
            const float fx = fminf(fmaxf(fl[p],      -4.0f), 3.99951171875f);
            const float fy = fminf(fmaxf(fl[HW + p], -4.0f), 3.99951171875f);
            const float xc = fminf(fmaxf((float)x + fx, 0.f), (float)(Wn - 1));
            const float yc = fminf(fmaxf((float)y + fy, 0.f), (float)(Hn - 1));
            const float x0f = floorf(xc), y0f = floorf(yc);
            lwx[k] = xc - x0f;  lwy[k] = yc - y0f;
            aL[k] = ((int)y0f - (Y - 4)) * WC + ((int)x0f - (XS - 4));
        }
        {
            const float fx = fminf(fmaxf(fr[p],      -4.0f), 3.99951171875f);
            const float fy = fminf(fmaxf(fr[HW + p], -4.0f), 3.99951171875f);
            const float xc = fminf(fmaxf((float)x + fx, 0.f), (float)(Wn - 1));
            const float yc = fminf(fmaxf((float)y + fy, 0.f), (float)(Hn - 1));
            const float x0f = floorf(xc), y0f = floorf(yc);
            rwx[k] = xc - x0f;  rwy[k] = yc - y0f;
            aR[k] = PSTR + ((int)y0f - (Y - 4)) * WC + ((int)x0f - (XS - 4));
        }
    }

    asm volatile("s_waitcnt vmcnt(0)" ::: "memory");  // channel-0 window landed
    __syncthreads();

    float local = 0.f;

    for (int c = 0; c < Cn; ++c) {
        // (1) gt loads FIRST (older than next DMA in vmcnt FIFO -> their
        //     consumption leaves the DMAs in flight)
        float g[PXT];
        #pragma unroll
        for (int k = 0; k < PXT; ++k) {
            const int i = k * BLK + tid;
            const int p = (Y + (i >> 6)) * Wn + XS + (i & 63);
            g[k] = Gb[(size_t)c * HW + p];
        }

        // (2) issue next channel's window DMA into the other buffer
        if (c < Cn - 1) {
            const float* __restrict__ Lc = Lb + (size_t)(c + 1) * HW;
            const float* __restrict__ Rc = Rb + (size_t)(c + 1) * HW;
            float* wb = win[(c + 1) & 1];
            #pragma unroll
            for (int k = 0; k < 4; ++k) {
                const float* src = ((k >> 1) ? Rc : Lc) + soff[k & 1];
                float* dst = &wb[(size_t)(k * BLK + wave16) * 4];
                GLOAD_LDS16(src, dst);
            }
        }

        // (3) sample channel c from current buffer (DMA latency hides here)
        const float* __restrict__ w = win[c & 1];
        #pragma unroll
        for (int k = 0; k < PXT; ++k) {
            const int a = aL[k];
            float v00 = w[a],      v01 = w[a + 1];
            float v10 = w[a + WC], v11 = w[a + WC + 1];
            float top = fmaf(lwx[k], v01 - v00, v00);
            float bot = fmaf(lwx[k], v11 - v10, v10);
            const float sL = fmaf(lwy[k], bot - top, top);
            const int a2 = aR[k];
            v00 = w[a2];      v01 = w[a2 + 1];
            v10 = w[a2 + WC]; v11 = w[a2 + WC + 1];
            top = fmaf(rwx[k], v01 - v00, v00);
            bot = fmaf(rwx[k], v11 - v10, v10);
            const float sR = fmaf(rwy[k], bot - top, top);
            local += fabsf(sL - g[k]) + fabsf(sR - g[k]);
        }

        // (4) one drain + barrier per channel
        if (c < Cn - 1) {
            asm volatile("s_waitcnt vmcnt(0)" ::: "memory");
            __syncthreads();
        }
    }

    // wave(64) shuffle reduce -> LDS cross-wave -> one f64 atomic per block
    #pragma unroll
    for (int off = 32; off > 0; off >>= 1)
        local += __shfl_down(local, off, 64);

    __shared__ float wsum[4];
    const int lane = tid & 63;
    const int wid  = tid >> 6;
    if (lane == 0) wsum[wid] = local;
    __syncthreads();
    if (tid == 0) {
        const float s = wsum[0] + wsum[1] + wsum[2] + wsum[3];
        atomicAdd(accum, (double)s);
    }
}

__global__ void finalize_kernel(const double* __restrict__ accum,
                                float* __restrict__ out) {
    out[0] = (float)(accum[0] / (double)NTOT);
}

extern "C" void kernel_launch(void* const* d_in, const int* in_sizes, int n_in,
                              void* d_out, int out_size, void* d_ws, size_t ws_size,
                              hipStream_t stream) {
    const float* L   = (const float*)d_in[0];
    const float* R   = (const float*)d_in[1];
    const float* flm = (const float*)d_in[2];
    const float* frm = (const float*)d_in[3];
    const float* gt  = (const float*)d_in[4];
    double* accum = (double*)d_ws;

    (void)hipMemsetAsync(accum, 0, sizeof(double), stream);
    warp_loss_kernel<<<NWG, BLK, 0, stream>>>(L, R, flm, frm, gt, accum);
    finalize_kernel<<<1, 1, 0, stream>>>(accum, (float*)d_out);
}

// Round 18
// 117.642 us; speedup vs baseline: 2.4198x; 1.0498x over previous
//
#include <hip/hip_runtime.h>

constexpr int Bn = 8, Cn = 3, Hn = 720, Wn = 1280;
constexpr int HW = Hn * Wn;                    // 921600 px per image
constexpr long long NTOT = (long long)Bn * Cn * HW;

constexpr int BLK  = 256;
constexpr int TH   = 16, TW = 64;              // output tile 16x64 = 1024 px
constexpr int TCOL = Wn / TW;                  // 20 tile-cols
constexpr int TPI  = (Hn / TH) * TCOL;         // 900 tiles per image
constexpr int NWG  = 8 * TPI;                  // 7200 blocks; bid&7 = image/XCD
constexpr int PXT  = (TH * TW) / BLK;          // 4 px per thread
constexpr int WR   = 24;                       // window rows: Y-4 .. Y+19 (border-replicated)
constexpr int WC   = 84;                       // window cols: XS-4 .. XS+79
constexpr int F4W  = WC / 4;                   // 21 f4 per window row
constexpr int F4P  = WR * F4W;                 // 504 real f4 per plane
constexpr int PSTR = 2048;                     // plane stride (floats): 512 f4, padded
constexpr int BUFF = 2 * PSTR;                 // 4096 floats = 16KB per channel

// async global->LDS DMA, 16B/lane; LDS dest = wave-uniform base + lane*16
#define GLOAD_LDS16(gsrc, ldst) \
    __builtin_amdgcn_global_load_lds( \
        (const __attribute__((address_space(1))) void*)(gsrc), \
        (__attribute__((address_space(3))) void*)(ldst), 16, 0, 0)

__global__ __launch_bounds__(256) void warp_loss_kernel(
        const float* __restrict__ L, const float* __restrict__ R,
        const float* __restrict__ Flm, const float* __restrict__ Frm,
        const float* __restrict__ G, double* __restrict__ accum) {
    // XCD k (= bid%8) owns image k; t = tile id, row-major sweep (halo in L2).
    // ONE latency epoch: flow+gt+all-3-channel DMAs issued up front,
    // one vmcnt(0)+barrier, then 3 pure LDS/VALU sampling phases.
    const int b    = blockIdx.x & 7;
    const int t    = blockIdx.x >> 3;          // [0, 900)
    const int trow = t / TCOL;
    const int tcol = t - trow * TCOL;
    const int Y    = trow * TH;
    const int XS   = tcol * TW;
    const int tid  = (int)threadIdx.x;

    const float* __restrict__ Lb = L + (size_t)b * Cn * HW;
    const float* __restrict__ Rb = R + (size_t)b * Cn * HW;
    const float* __restrict__ Gb = G + (size_t)b * Cn * HW;
    const float* __restrict__ fl = Flm + (size_t)b * 2 * HW;  // [0,HW)=x, [HW,2HW)=y
    const float* __restrict__ fr = Frm + (size_t)b * 2 * HW;

    __shared__ float win[Cn][BUFF];            // 48 KB: per-channel L+R windows
    __shared__ float wsum[4];

    // ---- per-px tap state (channel-invariant), coalesced flow loads ----
    int   aL[PXT], aR[PXT];
    float lwx[PXT], lwy[PXT], rwx[PXT], rwy[PXT];
    #pragma unroll
    for (int k = 0; k < PXT; ++k) {
        const int i = k * BLK + tid;
        const int r = i >> 6, cm = i & 63;
        const int y = Y + r, x = XS + cm;
        const int p = y * Wn + x;
        {
            const float fx = fminf(fmaxf(fl[p],      -4.0f), 3.99951171875f);
            const float fy = fminf(fmaxf(fl[HW + p], -4.0f), 3.99951171875f);
            const float xc = fminf(fmaxf((float)x + fx, 0.f), (float)(Wn - 1));
            const float yc = fminf(fmaxf((float)y + fy, 0.f), (float)(Hn - 1));
            const float x0f = floorf(xc), y0f = floorf(yc);
            lwx[k] = xc - x0f;  lwy[k] = yc - y0f;
            aL[k] = ((int)y0f - (Y - 4)) * WC + ((int)x0f - (XS - 4));
        }
        {
            const float fx = fminf(fmaxf(fr[p],      -4.0f), 3.99951171875f);
            const float fy = fminf(fmaxf(fr[HW + p], -4.0f), 3.99951171875f);
            const float xc = fminf(fmaxf((float)x + fx, 0.f), (float)(Wn - 1));
            const float yc = fminf(fmaxf((float)y + fy, 0.f), (float)(Hn - 1));
            const float x0f = floorf(xc), y0f = floorf(yc);
            rwx[k] = xc - x0f;  rwy[k] = yc - y0f;
            aR[k] = PSTR + ((int)y0f - (Y - 4)) * WC + ((int)x0f - (XS - 4));
        }
    }

    // ---- ALL gt loads up front, held in registers (12) ----
    float g[Cn][PXT];
    #pragma unroll
    for (int c = 0; c < Cn; ++c)
        #pragma unroll
        for (int k = 0; k < PXT; ++k) {
            const int i = k * BLK + tid;
            const int p = (Y + (i >> 6)) * Wn + XS + (i & 63);
            g[c][k] = Gb[(size_t)c * HW + p];
        }

    // ---- channel-invariant staging source offsets (pad slots clamp) ----
    int soff[2];
    #pragma unroll
    for (int k1 = 0; k1 < 2; ++k1) {
        const int f  = min(k1 * BLK + tid, F4P - 1);
        const int wr = f / F4W;
        const int c4 = f - wr * F4W;
        const int ys = min(max(Y - 4 + wr, 0), Hn - 1);
        const int xw = min(max(XS - 4 + c4 * 4, 0), Wn - 4);  // 16B-aligned, in-bounds
        soff[k1] = ys * Wn + xw;
    }
    const int wave16 = (tid & 192);            // wave-uniform slot base

    // ---- ALL 12 DMAs: 3 channels x {L plane (2), R plane (2)} ----
    #pragma unroll
    for (int c = 0; c < Cn; ++c) {
        const float* __restrict__ Lc = Lb + (size_t)c * HW;
        const float* __restrict__ Rc = Rb + (size_t)c * HW;
        #pragma unroll
        for (int k = 0; k < 4; ++k) {
            const float* src = ((k >> 1) ? Rc : Lc) + soff[k & 1];
            float* dst = &win[c][(size_t)((k & 1) * BLK + wave16) * 4 + (k >> 1) * PSTR];
            GLOAD_LDS16(src, dst);
        }
    }

    // ---- the ONLY drain + barrier ----
    asm volatile("s_waitcnt vmcnt(0)" ::: "memory");
    __builtin_amdgcn_sched_barrier(0);
    __syncthreads();

    // ---- 3 back-to-back sampling phases: pure LDS + VALU, zero syncs ----
    float local = 0.f;
    #pragma unroll
    for (int c = 0; c < Cn; ++c) {
        const float* __restrict__ w = win[c];
        #pragma unroll
        for (int k = 0; k < PXT; ++k) {
            const int a = aL[k];
            float v00 = w[a],      v01 = w[a + 1];
            float v10 = w[a + WC], v11 = w[a + WC + 1];
            float top = fmaf(lwx[k], v01 - v00, v00);
            float bot = fmaf(lwx[k], v11 - v10, v10);
            const float sL = fmaf(lwy[k], bot - top, top);
            const int a2 = aR[k];
            v00 = w[a2];      v01 = w[a2 + 1];
            v10 = w[a2 + WC]; v11 = w[a2 + WC + 1];
            top = fmaf(rwx[k], v01 - v00, v00);
            bot = fmaf(rwx[k], v11 - v10, v10);
            const float sR = fmaf(rwy[k], bot - top, top);
            local += fabsf(sL - g[c][k]) + fabsf(sR - g[c][k]);
        }
    }

    // wave(64) shuffle reduce -> LDS cross-wave -> one f64 atomic per block
    #pragma unroll
    for (int off = 32; off > 0; off >>= 1)
        local += __shfl_down(local, off, 64);

    const int lane = tid & 63;
    const int wid  = tid >> 6;
    if (lane == 0) wsum[wid] = local;
    __syncthreads();
    if (tid == 0) {
        const float s = wsum[0] + wsum[1] + wsum[2] + wsum[3];
        atomicAdd(accum, (double)s);
    }
}

__global__ void finalize_kernel(const double* __restrict__ accum,
                                float* __restrict__ out) {
    out[0] = (float)(accum[0] / (double)NTOT);
}

extern "C" void kernel_launch(void* const* d_in, const int* in_sizes, int n_in,
                              void* d_out, int out_size, void* d_ws, size_t ws_size,
                              hipStream_t stream) {
    const float* L   = (const float*)d_in[0];
    const float* R   = (const float*)d_in[1];
    const float* flm = (const float*)d_in[2];
    const float* frm = (const float*)d_in[3];
    const float* gt  = (const float*)d_in[4];
    double* accum = (double*)d_ws;

    (void)hipMemsetAsync(accum, 0, sizeof(double), stream);
    warp_loss_kernel<<<NWG, BLK, 0, stream>>>(L, R, flm, frm, gt, accum);
    finalize_kernel<<<1, 1, 0, stream>>>(accum, (float*)d_out);
}